// Round 6
// baseline (330.079 us; speedup 1.0000x reference)
//
#include <hip/hip_runtime.h>

#define MAT_N 256
#define TPB   512
#define ITERS 20
#define TSTRIDE 72   // f16 stride of transpose staging rows (mult of 8 -> b128-aligned)

typedef _Float16 half2v __attribute__((ext_vector_type(2)));

// DPP add: x += row_ror:<N>(x). VALU-pipe cross-lane, zero DS traffic.
template<int CTRL>
__device__ __forceinline__ float dpp_add(float x) {
    int s = __builtin_amdgcn_update_dpp(0, __builtin_bit_cast(int, x), CTRL, 0xF, 0xF, true);
    return x + __builtin_bit_cast(float, s);
}
// full 16-lane all-reduce (DPP rows = lanes 16k..16k+15)
__device__ __forceinline__ float allreduce16(float x) {
    x = dpp_add<0x121>(x);   // row_ror:1
    x = dpp_add<0x122>(x);   // row_ror:2
    x = dpp_add<0x124>(x);   // row_ror:4
    x = dpp_add<0x128>(x);   // row_ror:8
    return x;
}
__device__ __forceinline__ half2v pkrtz(float lo, float hi) {
    return __builtin_bit_cast(half2v, __builtin_amdgcn_cvt_pkrtz(lo, hi));
}
#if __has_builtin(__builtin_amdgcn_fdot2)
__device__ __forceinline__ float dot2(half2v a, half2v b, float c) {
    return __builtin_amdgcn_fdot2(a, b, c, false);   // v_dot2_f32_f16
}
#else
__device__ __forceinline__ float dot2(half2v a, half2v b, float c) {
    return c + (float)a.x * (float)b.x + (float)a.y * (float)b.y;
}
#endif

// R8: R7 counters showed 12.7k cyc/iter vs ~4.2k VALU issue + ~2.4k DS — the
// serial [colpass | bar | LDS-reduce (latency-chained, unhideable) | bar |
// rowpass] structure is ~2/3 stall. Fix: hold E AND E^T in registers (f16,
// 32+32 VGPR). Col pass becomes dot2 + DPP allreduce16, symmetric to the row
// pass: the LDS reduce phase is GONE. Per-iter LDS = two tiny broadcasts of
// f/g (swizzled, conflict-free 2-way b128 reads; predicated b32 writes).
// E^T built once at startup via 4-round 32KB staging transpose.
// f/g roundtrip stays f16 (same precision as R7, absmax ~1e-3); dot2
// accumulates in f32 (better than R7's f16 col partials).
__global__ __launch_bounds__(TPB)
__attribute__((amdgpu_waves_per_eu(4, 4)))
void sinkhorn_kernel(const float* __restrict__ x, float* __restrict__ out)
{
    const int t    = threadIdx.x;
    const int g16  = t >> 4;      // 0..31: E row-band AND E^T col-band
    const int rl   = t & 15;      // lane in DPP row: E col-tile AND E^T row-band
    const int row0 = g16 << 3;    // E rows row0..row0+7
    const int col0 = rl << 4;     // E cols col0..col0+15

    // word swizzle p(w) = w + 4*(w>>5): spreads 8-word groups over all banks;
    // groups of 8 words never cross a 32-block so b128 pairs stay contiguous.
    const int pb_fg  = (rl << 3) + ((rl >> 2) << 2);   // p(8*rl): f-read & g-read base
    const int wWrite = (g16 << 2) + rl;                // word this lane writes (rl<4)
    const int pWrite = wWrite + ((wWrite >> 5) << 2);  // p(wWrite)

    const size_t moff = (size_t)blockIdx.x * (MAT_N * MAT_N);
    const float* __restrict__ xm = x + moff;
    float* __restrict__       om = out + moff;

    __shared__ __align__(16) _Float16 stage[256 * TSTRIDE];  // transpose staging (one-time)
    __shared__ __align__(16) half2v   fbuf[140];             // f broadcast, swizzled f16 pairs
    __shared__ __align__(16) half2v   gbuf[140];             // g broadcast, swizzled f16 pairs
    __shared__ float2 gf[128];                               // f32 g for epilogue only

    // ---- load tile, E = exp(x), pack to f16 (RNE) ----
    half2v E[8][8];   // E[l][k]: row row0+l, cols (col0+2k, col0+2k+1)
#pragma unroll
    for (int l = 0; l < 8; ++l) {
        const float* rp = xm + (row0 + l) * MAT_N + col0;
        float4 a = ((const float4*)rp)[0];
        float4 b = ((const float4*)rp)[1];
        float4 c = ((const float4*)rp)[2];
        float4 d = ((const float4*)rp)[3];
        E[l][0] = (half2v){(_Float16)__expf(a.x), (_Float16)__expf(a.y)};
        E[l][1] = (half2v){(_Float16)__expf(a.z), (_Float16)__expf(a.w)};
        E[l][2] = (half2v){(_Float16)__expf(b.x), (_Float16)__expf(b.y)};
        E[l][3] = (half2v){(_Float16)__expf(b.z), (_Float16)__expf(b.w)};
        E[l][4] = (half2v){(_Float16)__expf(c.x), (_Float16)__expf(c.y)};
        E[l][5] = (half2v){(_Float16)__expf(c.z), (_Float16)__expf(c.w)};
        E[l][6] = (half2v){(_Float16)__expf(d.x), (_Float16)__expf(d.y)};
        E[l][7] = (half2v){(_Float16)__expf(d.z), (_Float16)__expf(d.w)};
    }

    // prefill f = 1 (all swizzled positions); ordered by the transpose barriers
    if (t < 140) fbuf[t] = (half2v){(_Float16)1.0f, (_Float16)1.0f};

    // ---- one-time transpose: build ET[c][j] = (E[16rl+2j][8g16+c], E[16rl+2j+1][...]) ----
    half2v ET[8][8];
#pragma unroll
    for (int q = 0; q < 4; ++q) {
        if ((rl >> 2) == q) {            // writers: col window [64q, 64q+64)
            const int coff = (rl & 3) << 4;
#pragma unroll
            for (int l = 0; l < 8; ++l) {
                const int idx = (row0 + l) * TSTRIDE + coff;
                *(float4*)&stage[idx] = make_float4(
                    __builtin_bit_cast(float, E[l][0]), __builtin_bit_cast(float, E[l][1]),
                    __builtin_bit_cast(float, E[l][2]), __builtin_bit_cast(float, E[l][3]));
                *(float4*)&stage[idx + 8] = make_float4(
                    __builtin_bit_cast(float, E[l][4]), __builtin_bit_cast(float, E[l][5]),
                    __builtin_bit_cast(float, E[l][6]), __builtin_bit_cast(float, E[l][7]));
            }
        }
        __syncthreads();
        if ((g16 >> 3) == q) {           // readers: ET cols 8*g16..+7 in this window
            const int coff = (g16 & 7) << 3;
#pragma unroll
            for (int j = 0; j < 8; ++j) {
                float4 ra = *(const float4*)&stage[((rl << 4) + (j << 1)) * TSTRIDE + coff];
                float4 rb = *(const float4*)&stage[((rl << 4) + (j << 1) + 1) * TSTRIDE + coff];
                half2v a0 = __builtin_bit_cast(half2v, ra.x), b0 = __builtin_bit_cast(half2v, rb.x);
                half2v a1 = __builtin_bit_cast(half2v, ra.y), b1 = __builtin_bit_cast(half2v, rb.y);
                half2v a2 = __builtin_bit_cast(half2v, ra.z), b2 = __builtin_bit_cast(half2v, rb.z);
                half2v a3 = __builtin_bit_cast(half2v, ra.w), b3 = __builtin_bit_cast(half2v, rb.w);
                ET[0][j] = (half2v){a0.x, b0.x};  ET[1][j] = (half2v){a0.y, b0.y};
                ET[2][j] = (half2v){a1.x, b1.x};  ET[3][j] = (half2v){a1.y, b1.y};
                ET[4][j] = (half2v){a2.x, b2.x};  ET[5][j] = (half2v){a2.y, b2.y};
                ET[6][j] = (half2v){a3.x, b3.x};  ET[7][j] = (half2v){a3.y, b3.y};
            }
        }
        __syncthreads();
    }

    float fv[8];

    for (int it = 0; it < ITERS; ++it) {
        // ---------- phase 1: col pass g[c] = 1 / sum_r E[r][c] f[r] ----------
        // read f pairs for rows 16*rl..+15 (conflict-free 2-way b128s)
        float4 fa = *(const float4*)&fbuf[pb_fg];
        float4 fb = *(const float4*)&fbuf[pb_fg + 4];
        half2v fp0 = __builtin_bit_cast(half2v, fa.x), fp1 = __builtin_bit_cast(half2v, fa.y);
        half2v fp2 = __builtin_bit_cast(half2v, fa.z), fp3 = __builtin_bit_cast(half2v, fa.w);
        half2v fp4 = __builtin_bit_cast(half2v, fb.x), fp5 = __builtin_bit_cast(half2v, fb.y);
        half2v fp6 = __builtin_bit_cast(half2v, fb.z), fp7 = __builtin_bit_cast(half2v, fb.w);

        float gv[8];
#pragma unroll
        for (int c = 0; c < 8; ++c) {
            float s = dot2(ET[c][0], fp0, 0.0f);
            s = dot2(ET[c][1], fp1, s);
            s = dot2(ET[c][2], fp2, s);
            s = dot2(ET[c][3], fp3, s);
            s = dot2(ET[c][4], fp4, s);
            s = dot2(ET[c][5], fp5, s);
            s = dot2(ET[c][6], fp6, s);
            s = dot2(ET[c][7], fp7, s);
            s = allreduce16(s);                 // sum over the 16 row-bands
            gv[c] = __builtin_amdgcn_rcpf(s);
        }
        // broadcast g: lane rl<4 writes pair (static cndmask select, no dyn index)
        {
            float glo = rl == 1 ? gv[2] : rl == 2 ? gv[4] : rl == 3 ? gv[6] : gv[0];
            float ghi = rl == 1 ? gv[3] : rl == 2 ? gv[5] : rl == 3 ? gv[7] : gv[1];
            if (rl < 4) {
                gbuf[pWrite] = pkrtz(glo, ghi);
                if (it == ITERS - 1) gf[wWrite] = make_float2(glo, ghi);
            }
        }
        __syncthreads();

        // ---------- phase 2: row pass f[l] = 1 / sum_c E[l][c] g[c] ----------
        float4 ga = *(const float4*)&gbuf[pb_fg];
        float4 gb = *(const float4*)&gbuf[pb_fg + 4];
        half2v g0 = __builtin_bit_cast(half2v, ga.x), g1 = __builtin_bit_cast(half2v, ga.y);
        half2v g2 = __builtin_bit_cast(half2v, ga.z), g3 = __builtin_bit_cast(half2v, ga.w);
        half2v g4 = __builtin_bit_cast(half2v, gb.x), g5 = __builtin_bit_cast(half2v, gb.y);
        half2v g6 = __builtin_bit_cast(half2v, gb.z), g7 = __builtin_bit_cast(half2v, gb.w);

#pragma unroll
        for (int l = 0; l < 8; ++l) {
            float s = dot2(E[l][0], g0, 0.0f);
            s = dot2(E[l][1], g1, s);
            s = dot2(E[l][2], g2, s);
            s = dot2(E[l][3], g3, s);
            s = dot2(E[l][4], g4, s);
            s = dot2(E[l][5], g5, s);
            s = dot2(E[l][6], g6, s);
            s = dot2(E[l][7], g7, s);
            s = allreduce16(s);                 // sum over the 16 col-tiles
            fv[l] = __builtin_amdgcn_rcpf(s);
        }
        // broadcast f
        {
            float flo = rl == 1 ? fv[2] : rl == 2 ? fv[4] : rl == 3 ? fv[6] : fv[0];
            float fhi = rl == 1 ? fv[3] : rl == 2 ? fv[5] : rl == 3 ? fv[7] : fv[1];
            if (rl < 4) fbuf[pWrite] = pkrtz(flo, fhi);
        }
        __syncthreads();
    }

    // ---------- output: out = E * f[row] * g[col] (f32 g from gf) ----------
    float Gc[16];
#pragma unroll
    for (int i = 0; i < 8; ++i) {
        float2 gg = gf[(rl << 3) + i];
        Gc[2 * i]     = gg.x;
        Gc[2 * i + 1] = gg.y;
    }
#pragma unroll
    for (int l = 0; l < 8; ++l) {
        float fr = fv[l];
        float* rp = om + (row0 + l) * MAT_N + col0;
        float o[16];
#pragma unroll
        for (int k = 0; k < 8; ++k) {
            o[2 * k]     = (float)E[l][k].x * fr * Gc[2 * k];
            o[2 * k + 1] = (float)E[l][k].y * fr * Gc[2 * k + 1];
        }
        ((float4*)rp)[0] = make_float4(o[0],  o[1],  o[2],  o[3]);
        ((float4*)rp)[1] = make_float4(o[4],  o[5],  o[6],  o[7]);
        ((float4*)rp)[2] = make_float4(o[8],  o[9],  o[10], o[11]);
        ((float4*)rp)[3] = make_float4(o[12], o[13], o[14], o[15]);
    }
}

extern "C" void kernel_launch(void* const* d_in, const int* in_sizes, int n_in,
                              void* d_out, int out_size, void* d_ws, size_t ws_size,
                              hipStream_t stream) {
    const float* x = (const float*)d_in[0];
    float* out = (float*)d_out;
    const int nmat = in_sizes[0] / (MAT_N * MAT_N);   // 512
    sinkhorn_kernel<<<nmat, TPB, 0, stream>>>(x, out);
}